// Round 11
// baseline (151.372 us; speedup 1.0000x reference)
//
#include <hip/hip_runtime.h>

#define DIM 64
#define MTILE 32         // rows per block -> 2048 blocks (8/CU of work)
#define THREADS 256
#define T_LEN 2048
#define SMARGT 1.3e-3f   // widened cut: 7.95e-4 pairwise + 1.87e-4 bf16-store + slack
#define RCAP 16          // per-row candidate list capacity (expected ~3-4 used)
#define RT_N 2           // row-tiles (16 rows each) per block
#define XP 68            // xstage pitch in floats (272B = 17*16B, float4-aligned rows)
#define CQP 66           // epilogue codebook-row staging pitch (float2-aligned, 2-way-free)
#define RLP 17           // rlist pitch in ushorts

typedef __attribute__((ext_vector_type(8))) short short8;
typedef __attribute__((ext_vector_type(4))) float f32x4;

// monotone order-preserving map float -> u32
__device__ __forceinline__ unsigned int fmap32(float s) {
    unsigned int b = __float_as_uint(s);
    return (b & 0x80000000u) ? ~b : (b | 0x80000000u);
}
__device__ __forceinline__ float funmap32(unsigned int m) {
    unsigned int b = (m & 0x80000000u) ? (m & 0x7fffffffu) : ~m;
    return __uint_as_float(b);
}
// fp32 -> bf16 RTNE
__device__ __forceinline__ unsigned int f2bf(float f) {
    unsigned int u = __float_as_uint(f);
    return (u + 0x7FFFu + ((u >> 16) & 1u)) >> 16;
}
// numpy pairwise-sum (n=64 scalar blocked path) combine tree over 8 partials
__device__ __forceinline__ float np_combine8(const float* r) {
    return __fadd_rn(__fadd_rn(__fadd_rn(r[0], r[1]), __fadd_rn(r[2], r[3])),
                     __fadd_rn(__fadd_rn(r[4], r[5]), __fadd_rn(r[6], r[7])));
}
// numpy n=64 squared-norm register routine (verified r2-r6). Generic pointer
// (works on LDS xstage rows); float4 accesses must be 16B-aligned.
__device__ __forceinline__ float np_norm64(const float* p) {
    const float4* c4 = (const float4*)p;
    float r8[8];
    {
        float4 a = c4[0], b = c4[1];
        r8[0] = __fmul_rn(a.x, a.x); r8[1] = __fmul_rn(a.y, a.y);
        r8[2] = __fmul_rn(a.z, a.z); r8[3] = __fmul_rn(a.w, a.w);
        r8[4] = __fmul_rn(b.x, b.x); r8[5] = __fmul_rn(b.y, b.y);
        r8[6] = __fmul_rn(b.z, b.z); r8[7] = __fmul_rn(b.w, b.w);
    }
    #pragma unroll
    for (int m = 1; m < 8; ++m) {
        float4 a = c4[2 * m], b = c4[2 * m + 1];
        r8[0] = __fadd_rn(r8[0], __fmul_rn(a.x, a.x));
        r8[1] = __fadd_rn(r8[1], __fmul_rn(a.y, a.y));
        r8[2] = __fadd_rn(r8[2], __fmul_rn(a.z, a.z));
        r8[3] = __fadd_rn(r8[3], __fmul_rn(a.w, a.w));
        r8[4] = __fadd_rn(r8[4], __fmul_rn(b.x, b.x));
        r8[5] = __fadd_rn(r8[5], __fmul_rn(b.y, b.y));
        r8[6] = __fadd_rn(r8[6], __fmul_rn(b.z, b.z));
        r8[7] = __fadd_rn(r8[7], __fmul_rn(b.w, b.w));
    }
    return np_combine8(r8);
}
// numpy-bit-exact distance key, STREAMING register form (r9; ~17 live VGPRs).
// Per m: load 8 floats, update the 8 r8 square-partials (m-ascending, same
// order as np_norm64) and the serial 64-FMA dot chain (element order 0..63).
// Each dependency chain sees the identical op sequence as r5 -> bit-exact.
__device__ __forceinline__ unsigned long long np_key_full(
        const float* xr, const float* cr, float an, int k) {
    const float4* c4p = (const float4*)cr;
    float r8[8];
    float acc = 0.0f;
    {
        float4 a = c4p[0], b = c4p[1];
        r8[0] = __fmul_rn(a.x, a.x); r8[1] = __fmul_rn(a.y, a.y);
        r8[2] = __fmul_rn(a.z, a.z); r8[3] = __fmul_rn(a.w, a.w);
        r8[4] = __fmul_rn(b.x, b.x); r8[5] = __fmul_rn(b.y, b.y);
        r8[6] = __fmul_rn(b.z, b.z); r8[7] = __fmul_rn(b.w, b.w);
        acc = __fmaf_rn(xr[0], a.x, acc); acc = __fmaf_rn(xr[1], a.y, acc);
        acc = __fmaf_rn(xr[2], a.z, acc); acc = __fmaf_rn(xr[3], a.w, acc);
        acc = __fmaf_rn(xr[4], b.x, acc); acc = __fmaf_rn(xr[5], b.y, acc);
        acc = __fmaf_rn(xr[6], b.z, acc); acc = __fmaf_rn(xr[7], b.w, acc);
    }
    #pragma unroll
    for (int m = 1; m < 8; ++m) {
        float4 a = c4p[2 * m], b = c4p[2 * m + 1];
        r8[0] = __fadd_rn(r8[0], __fmul_rn(a.x, a.x));
        r8[1] = __fadd_rn(r8[1], __fmul_rn(a.y, a.y));
        r8[2] = __fadd_rn(r8[2], __fmul_rn(a.z, a.z));
        r8[3] = __fadd_rn(r8[3], __fmul_rn(a.w, a.w));
        r8[4] = __fadd_rn(r8[4], __fmul_rn(b.x, b.x));
        r8[5] = __fadd_rn(r8[5], __fmul_rn(b.y, b.y));
        r8[6] = __fadd_rn(r8[6], __fmul_rn(b.z, b.z));
        r8[7] = __fadd_rn(r8[7], __fmul_rn(b.w, b.w));
        const float* xm = xr + 8 * m;
        acc = __fmaf_rn(xm[0], a.x, acc); acc = __fmaf_rn(xm[1], a.y, acc);
        acc = __fmaf_rn(xm[2], a.z, acc); acc = __fmaf_rn(xm[3], a.w, acc);
        acc = __fmaf_rn(xm[4], b.x, acc); acc = __fmaf_rn(xm[5], b.y, acc);
        acc = __fmaf_rn(xm[6], b.z, acc); acc = __fmaf_rn(xm[7], b.w, acc);
    }
    float bn = np_combine8(r8);
    float t1 = __fadd_rn(an, bn);
    float d  = __fsub_rn(t1, __fmul_rn(2.0f, acc));
    return ((unsigned long long)fmap32(d) << 12) | (unsigned long long)k;
}

__global__ void vq_init_ws(double* ws) { ws[0] = 0.0; }

__global__ void vq_finalize_atomic(const double* __restrict__ ws,
                                   float* __restrict__ out_loss, int n_el) {
    out_loss[0] = (float)(1.25 * ws[0] / (double)n_el);
}

// reduces 2048 per-block partials (launched with 1024 threads)
__global__ void vq_finalize_part(const double* __restrict__ ws,
                                 float* __restrict__ out_loss, int n_el) {
    __shared__ double red[16];
    double v = ws[threadIdx.x] + ws[threadIdx.x + 1024];
    #pragma unroll
    for (int off = 32; off > 0; off >>= 1) v += __shfl_down(v, off, 64);
    if ((threadIdx.x & 63) == 0) red[threadIdx.x >> 6] = v;
    __syncthreads();
    if (threadIdx.x == 0) {
        double s = 0.0;
        #pragma unroll
        for (int i = 0; i < 16; ++i) s += red[i];
        out_loss[0] = (float)(1.25 * s / (double)n_el);
    }
}

// one-time fp32 -> bf16 codebook conversion + PRE-SWIZZLE into per-lane MFMA
// fragment order (proven r7): swz[(tile*2 + half)*64 + lane] = 8 bf16 of code
// (tile*16 + (lane&15)), dims half*32 + (lane>>4)*8 .. +7. Scan loads become
// 64 lanes x 16B CONTIGUOUS. Same f2bf bits as in-kernel conversion.
__global__ void vq_cvt_swz(const float* __restrict__ cb,
                           unsigned short* __restrict__ swz) {
    const int g = blockIdx.x * 256 + threadIdx.x;   // 0..8191 fragment groups
    const int lane = g & 63;
    const int half = (g >> 6) & 1;
    const int tile = g >> 7;                        // 0..63
    const int code = tile * 16 + (lane & 15);
    const int d0   = half * 32 + (lane >> 4) * 8;
    const float4* s = (const float4*)(cb + (size_t)code * DIM + d0);
    float4 v0 = s[0], v1 = s[1];
    short8 o;
    o[0] = (short)f2bf(v0.x); o[1] = (short)f2bf(v0.y);
    o[2] = (short)f2bf(v0.z); o[3] = (short)f2bf(v0.w);
    o[4] = (short)f2bf(v1.x); o[5] = (short)f2bf(v1.y);
    o[6] = (short)f2bf(v1.z); o[7] = (short)f2bf(v1.w);
    *(short8*)(swz + (size_t)g * 8) = o;
}

// Round-11: SINGLE-scan. Pass 1 stores each tile's 4 s values packed bf16 in
// registers (spk[2][16][2], 64 VGPR, statically indexed via full unroll).
// After the exact smax merge, capture is pure register unpack+compare — the
// old pass 2's 16 L2 loads + 64 MFMAs per wave are deleted. Margin: widened
// cut SMARGT=1.3e-3 covers proven pairwise 7.95e-4 + bf16-store err <=1.87e-4
// (|s|<=0.09 from chi2(64) tail over 65536 rows) -> strict superset of the
// r4-proven capture set; refine stays np-bit-exact. (256,4): no spill (r8/r9
// lesson: forcing occupancy spills; cap 128 lets the allocator breathe).
template<int SWZ>
__global__ __launch_bounds__(THREADS, 4) void vq_main(
        const float* __restrict__ x,
        const float* __restrict__ cb,
        const unsigned short* __restrict__ swz,
        float* __restrict__ out_q,
        float* __restrict__ out_idx,
        double* __restrict__ wsd,
        int use_partials)
{
    __shared__ float xstage[MTILE * XP];        // 8704 B; reused as cpq in epilogue
    __shared__ float wsm[4][MTILE];             // per-wave row smax
    __shared__ unsigned short rlist[MTILE * RLP];
    __shared__ int   rcnt[MTILE];
    __shared__ float anorm[MTILE];
    __shared__ int   kstar[MTILE];
    __shared__ double lossd[MTILE];
    __shared__ int   ovfrows[MTILE];
    __shared__ int   ovfcnt;

    const int tid  = threadIdx.x;
    const int lane = tid & 63;
    const int wv   = tid >> 6;         // wave 0..3
    const int col  = lane & 15;
    const int quad = lane >> 4;        // 0..3
    const int r0   = blockIdx.x * MTILE;

    if (tid == 0) ovfcnt = 0;
    if (tid < MTILE) rcnt[tid] = 0;

    // ---- stage x rows into LDS, coalesced (exact fp32 bits); 8 thr/row ----
    {
        const int rr = tid >> 3, part = tid & 7;
        const float4* xs = (const float4*)(x + (size_t)(r0 + rr) * DIM + part * 8);
        float4 v0 = xs[0], v1 = xs[1];
        float* dst = &xstage[rr * XP + part * 8];
        *(float4*)&dst[0] = v0;
        *(float4*)&dst[4] = v1;
    }
    __syncthreads();

    // ---- A_n from staged rows (np-exact) ----
    if (tid < MTILE) anorm[tid] = np_norm64(&xstage[tid * XP]);

    // ---- A (row) fragments from LDS with in-lane bf16 convert ----
    short8 afr[RT_N][2];
    #pragma unroll
    for (int mt = 0; mt < RT_N; ++mt) {
        #pragma unroll
        for (int kh = 0; kh < 2; ++kh) {
            const float* ap = &xstage[(mt * 16 + col) * XP + kh * 32 + quad * 8];
            float4 a = *(const float4*)ap;
            float4 b = *(const float4*)(ap + 4);
            short8 s;
            s[0] = (short)f2bf(a.x); s[1] = (short)f2bf(a.y);
            s[2] = (short)f2bf(a.z); s[3] = (short)f2bf(a.w);
            s[4] = (short)f2bf(b.x); s[5] = (short)f2bf(b.y);
            s[6] = (short)f2bf(b.z); s[7] = (short)f2bf(b.w);
            afr[mt][kh] = s;
        }
    }

    // per-lane bases. SWZ path: wave wv's tile t is kt=4t+wv; fragment group
    // base = kt*128 + half*64 + lane (x8 shorts). Coalesced 1KB per load.
    const unsigned short* sw  = swz + (size_t)wv * 1024 + (size_t)lane * 8;
    const float*          bp0 = cb  + (size_t)(wv * 16 + col) * DIM + quad * 8;

    // ========== SINGLE SCAN: MFMA -> exact fmax + packed bf16 s-store ==========
    float runsmax[RT_N];
    #pragma unroll
    for (int rt = 0; rt < RT_N; ++rt) runsmax[rt] = -3.4e38f;
    unsigned int spk[RT_N][16][2];   // statically indexed (full unroll) -> VGPRs

    #pragma unroll
    for (int t = 0; t < 16; ++t) {
        short8 b0, b1;
        if constexpr (SWZ) {
            const unsigned short* p = sw + (size_t)t * 4096;
            b0 = *(const short8*)(p);
            b1 = *(const short8*)(p + 512);
        } else {
            const float* p = bp0 + (size_t)t * 4096;
            float4 ca = *(const float4*)(p);
            float4 cb4 = *(const float4*)(p + 4);
            float4 cc = *(const float4*)(p + 32);
            float4 cd = *(const float4*)(p + 36);
            b0[0] = (short)f2bf(ca.x);  b0[1] = (short)f2bf(ca.y);
            b0[2] = (short)f2bf(ca.z);  b0[3] = (short)f2bf(ca.w);
            b0[4] = (short)f2bf(cb4.x); b0[5] = (short)f2bf(cb4.y);
            b0[6] = (short)f2bf(cb4.z); b0[7] = (short)f2bf(cb4.w);
            b1[0] = (short)f2bf(cc.x);  b1[1] = (short)f2bf(cc.y);
            b1[2] = (short)f2bf(cc.z);  b1[3] = (short)f2bf(cc.w);
            b1[4] = (short)f2bf(cd.x);  b1[5] = (short)f2bf(cd.y);
            b1[6] = (short)f2bf(cd.z);  b1[7] = (short)f2bf(cd.w);
        }
        #pragma unroll
        for (int rt = 0; rt < RT_N; ++rt) {
            f32x4 acc = {0.f, 0.f, 0.f, 0.f};
            acc = __builtin_amdgcn_mfma_f32_16x16x32_bf16(b0, afr[rt][0], acc, 0, 0, 0);
            acc = __builtin_amdgcn_mfma_f32_16x16x32_bf16(b1, afr[rt][1], acc, 0, 0, 0);
            runsmax[rt] = fmaxf(runsmax[rt],
                fmaxf(fmaxf(acc[0], acc[1]), fmaxf(acc[2], acc[3])));
            spk[rt][t][0] = (f2bf(acc[0]) << 16) | f2bf(acc[1]);
            spk[rt][t][1] = (f2bf(acc[2]) << 16) | f2bf(acc[3]);
        }
    }

    // merge: quads (same row) then waves via LDS -> exact final smax per row
    #pragma unroll
    for (int rt = 0; rt < RT_N; ++rt) {
        float mw = fmaxf(runsmax[rt], __shfl_xor(runsmax[rt], 16, 64));
        mw = fmaxf(mw, __shfl_xor(mw, 32, 64));
        if (quad == 0) wsm[wv][rt * 16 + col] = mw;
    }
    __syncthreads();
    float scut[RT_N];
    #pragma unroll
    for (int rt = 0; rt < RT_N; ++rt) {
        const int row = rt * 16 + col;
        float sm = fmaxf(fmaxf(wsm[0][row], wsm[1][row]),
                         fmaxf(wsm[2][row], wsm[3][row]));
        scut[rt] = sm - SMARGT;
    }

    // ========== capture from registers (no loads, no MFMA) ==========
    #pragma unroll
    for (int t = 0; t < 16; ++t) {
        const int kb = (t * 4 + wv) * 16 + quad * 4;
        #pragma unroll
        for (int rt = 0; rt < RT_N; ++rt) {
            const unsigned int p0 = spk[rt][t][0];
            const unsigned int p1 = spk[rt][t][1];
            const float s0 = __uint_as_float(p0 & 0xFFFF0000u);
            const float s1 = __uint_as_float(p0 << 16);
            const float s2 = __uint_as_float(p1 & 0xFFFF0000u);
            const float s3 = __uint_as_float(p1 << 16);
            const float m = fmaxf(fmaxf(s0, s1), fmaxf(s2, s3));
            if (m >= scut[rt]) {               // rare (~3-4 hits/row total)
                const int row = rt * 16 + col;
                if (s0 >= scut[rt]) { int p2 = atomicAdd(&rcnt[row], 1);
                    if (p2 < RCAP) rlist[row * RLP + p2] = (unsigned short)(kb + 0); }
                if (s1 >= scut[rt]) { int p2 = atomicAdd(&rcnt[row], 1);
                    if (p2 < RCAP) rlist[row * RLP + p2] = (unsigned short)(kb + 1); }
                if (s2 >= scut[rt]) { int p2 = atomicAdd(&rcnt[row], 1);
                    if (p2 < RCAP) rlist[row * RLP + p2] = (unsigned short)(kb + 2); }
                if (s3 >= scut[rt]) { int p2 = atomicAdd(&rcnt[row], 1);
                    if (p2 < RCAP) rlist[row * RLP + p2] = (unsigned short)(kb + 3); }
            }
        }
    }
    __syncthreads();   // rlist complete

    // ---- refine: 8 threads/row (j strided), np-bit-exact keys, shfl merge ----
    {
        const int r  = tid >> 3;      // row 0..31 (threads 8r..8r+7: same wave)
        const int j0 = tid & 7;
        const int n  = rcnt[r];
        unsigned long long best = ~0ULL;
        if (n <= RCAP) {
            const float an = anorm[r];
            const float* xr = &xstage[r * XP];
            for (int j = j0; j < n; j += 8) {
                const int k = rlist[r * RLP + j];
                unsigned long long key = np_key_full(xr, cb + (size_t)k * DIM, an, k);
                best = (key < best) ? key : best;
            }
        }
        unsigned long long o = __shfl_xor(best, 1, 64);
        best = (o < best) ? o : best;
        o = __shfl_xor(best, 2, 64);
        best = (o < best) ? o : best;
        o = __shfl_xor(best, 4, 64);
        best = (o < best) ? o : best;
        if (j0 == 0) {
            if (n > RCAP || best == ~0ULL) {
                int si = atomicAdd(&ovfcnt, 1);
                ovfrows[si] = r;
            } else {
                kstar[r] = (int)(best & 0xFFFULL);
                lossd[r] = (double)funmap32((unsigned int)(best >> 12));
            }
        }
    }
    __syncthreads();

    // ---- wave-parallel exhaustive np fallback for overflowed rows (rare) ----
    const int ovfn = ovfcnt;
    for (int i = wv; i < ovfn; i += 4) {
        const int row = ovfrows[i];
        const float* xr2 = &xstage[row * XP];   // same-address LDS broadcasts
        const float an2 = anorm[row];
        unsigned long long b2 = ~0ULL;
        for (int j = 0; j < 16; ++j) {
            int k = lane * 16 + j;
            unsigned long long key = np_key_full(xr2, cb + (size_t)k * DIM, an2, k);
            b2 = (key < b2) ? key : b2;
        }
        #pragma unroll
        for (int off = 1; off < 64; off <<= 1) {
            unsigned long long o = __shfl_xor(b2, off, 64);
            b2 = (o < b2) ? o : b2;
        }
        if (lane == 0) {
            kstar[row] = (int)(b2 & 0xFFFULL);
            lossd[row] = (double)funmap32((unsigned int)(b2 >> 12));
        }
    }
    __syncthreads();

    // ---- epilogue: indices; stage selected cb rows into LDS (de-gathered),
    //      then transposed quantized stores; loss reduce (verified) ----
    if (tid < MTILE) out_idx[r0 + tid] = (float)kstar[tid];

    float* cpq = xstage;   // xstage dead from here; reuse with pitch CQP=66
    {
        const int r = tid >> 3, part = tid & 7;
        const int kq = kstar[r];
        const float4* cp = (const float4*)(cb + (size_t)kq * DIM + part * 8);
        float4 v0 = cp[0], v1 = cp[1];
        float* dst = &cpq[r * CQP + part * 8];   // 8B-aligned: float2 writes
        *(float2*)&dst[0] = make_float2(v0.x, v0.y);
        *(float2*)&dst[2] = make_float2(v0.z, v0.w);
        *(float2*)&dst[4] = make_float2(v1.x, v1.y);
        *(float2*)&dst[6] = make_float2(v1.z, v1.w);
    }
    __syncthreads();

    const int bb = r0 / T_LEN;
    const int t0 = r0 % T_LEN;
    const int t  = tid & 31, part = tid >> 5;   // part 0..7
    #pragma unroll
    for (int it = 0; it < 8; ++it) {
        int d = it * 8 + part;
        out_q[((size_t)bb * DIM + d) * T_LEN + (t0 + t)] = cpq[t * CQP + d];
    }

    if (tid < 64) {
        double v = (tid < MTILE) ? lossd[tid] : 0.0;
        #pragma unroll
        for (int off = 32; off > 0; off >>= 1) v += __shfl_down(v, off, 64);
        if (tid == 0) {
            if (use_partials) wsd[blockIdx.x] = v;
            else atomicAdd(wsd, v);
        }
    }
}

extern "C" void kernel_launch(void* const* d_in, const int* in_sizes, int n_in,
                              void* d_out, int out_size, void* d_ws, size_t ws_size,
                              hipStream_t stream) {
    const float* x  = (const float*)d_in[0];
    const float* cb = (const float*)d_in[1];
    float* out = (float*)d_out;

    const int n_x = in_sizes[0];           // 4194304
    const int n_rows = n_x / DIM;          // 65536
    const int n_blocks = n_rows / MTILE;   // 2048

    float* out_q    = out;                    // [B, D, T]
    float* out_loss = out + (size_t)n_x;      // scalar
    float* out_idx  = out + (size_t)n_x + 1;  // [B, T] as float
    double* wsd = (double*)d_ws;

    const size_t need_part = (size_t)n_blocks * sizeof(double);
    const int use_partials = (ws_size >= need_part) ? 1 : 0;
    const size_t cb_off = use_partials ? ((need_part + 15) & ~(size_t)15) : (size_t)16;
    const int use_swz = (ws_size >= cb_off + 1024 * DIM * sizeof(unsigned short)) ? 1 : 0;
    unsigned short* swz = (unsigned short*)((char*)d_ws + cb_off);

    if (!use_partials) vq_init_ws<<<1, 1, 0, stream>>>(wsd);
    if (use_swz) {
        vq_cvt_swz<<<32, 256, 0, stream>>>(cb, swz);
        vq_main<1><<<n_blocks, THREADS, 0, stream>>>(x, cb, swz, out_q, out_idx,
                                                     wsd, use_partials);
    } else {
        vq_main<0><<<n_blocks, THREADS, 0, stream>>>(x, cb, (const unsigned short*)cb,
                                                     out_q, out_idx, wsd, use_partials);
    }
    if (use_partials) vq_finalize_part<<<1, 1024, 0, stream>>>(wsd, out_loss, n_x);
    else vq_finalize_atomic<<<1, 1, 0, stream>>>(wsd, out_loss, n_x);
}

// Round 12
// 104.394 us; speedup vs baseline: 1.4500x; 1.4500x over previous
//
#include <hip/hip_runtime.h>

#define DIM 64
#define MTILE 32         // rows per block -> 2048 blocks (8/CU of work)
#define THREADS 256
#define T_LEN 2048
#define SMARG 1e-3f      // s-space capture margin (needs 7.95e-4: pairwise 1.53e-3/2 + bn/2)
#define RCAP 16          // per-row candidate list capacity (expected ~2-3 used)
#define RT_N 2           // row-tiles (16 rows each) per block
#define XP 68            // xstage pitch in floats (272B = 17*16B, float4-aligned rows)
#define CQP 66           // epilogue codebook-row staging pitch (float2-aligned, 2-way-free)
#define RLP 17           // rlist pitch in ushorts

typedef __attribute__((ext_vector_type(8))) short short8;
typedef __attribute__((ext_vector_type(4))) float f32x4;

// monotone order-preserving map float -> u32
__device__ __forceinline__ unsigned int fmap32(float s) {
    unsigned int b = __float_as_uint(s);
    return (b & 0x80000000u) ? ~b : (b | 0x80000000u);
}
__device__ __forceinline__ float funmap32(unsigned int m) {
    unsigned int b = (m & 0x80000000u) ? (m & 0x7fffffffu) : ~m;
    return __uint_as_float(b);
}
// fp32 -> bf16 RTNE
__device__ __forceinline__ unsigned int f2bf(float f) {
    unsigned int u = __float_as_uint(f);
    return (u + 0x7FFFu + ((u >> 16) & 1u)) >> 16;
}
// numpy pairwise-sum (n=64 scalar blocked path) combine tree over 8 partials
__device__ __forceinline__ float np_combine8(const float* r) {
    return __fadd_rn(__fadd_rn(__fadd_rn(r[0], r[1]), __fadd_rn(r[2], r[3])),
                     __fadd_rn(__fadd_rn(r[4], r[5]), __fadd_rn(r[6], r[7])));
}
// numpy n=64 squared-norm register routine (verified r2-r6). Generic pointer
// (works on LDS xstage rows); float4 accesses must be 16B-aligned.
__device__ __forceinline__ float np_norm64(const float* p) {
    const float4* c4 = (const float4*)p;
    float r8[8];
    {
        float4 a = c4[0], b = c4[1];
        r8[0] = __fmul_rn(a.x, a.x); r8[1] = __fmul_rn(a.y, a.y);
        r8[2] = __fmul_rn(a.z, a.z); r8[3] = __fmul_rn(a.w, a.w);
        r8[4] = __fmul_rn(b.x, b.x); r8[5] = __fmul_rn(b.y, b.y);
        r8[6] = __fmul_rn(b.z, b.z); r8[7] = __fmul_rn(b.w, b.w);
    }
    #pragma unroll
    for (int m = 1; m < 8; ++m) {
        float4 a = c4[2 * m], b = c4[2 * m + 1];
        r8[0] = __fadd_rn(r8[0], __fmul_rn(a.x, a.x));
        r8[1] = __fadd_rn(r8[1], __fmul_rn(a.y, a.y));
        r8[2] = __fadd_rn(r8[2], __fmul_rn(a.z, a.z));
        r8[3] = __fadd_rn(r8[3], __fmul_rn(a.w, a.w));
        r8[4] = __fadd_rn(r8[4], __fmul_rn(b.x, b.x));
        r8[5] = __fadd_rn(r8[5], __fmul_rn(b.y, b.y));
        r8[6] = __fadd_rn(r8[6], __fmul_rn(b.z, b.z));
        r8[7] = __fadd_rn(r8[7], __fmul_rn(b.w, b.w));
    }
    return np_combine8(r8);
}
// numpy-bit-exact distance key, STREAMING register form (r9; ~17 live VGPRs).
// Per m: load 8 floats, update the 8 r8 square-partials (m-ascending, same
// order as np_norm64) and the serial 64-FMA dot chain (element order 0..63).
// Each dependency chain sees the identical op sequence as r5 -> bit-exact.
__device__ __forceinline__ unsigned long long np_key_full(
        const float* xr, const float* cr, float an, int k) {
    const float4* c4p = (const float4*)cr;
    float r8[8];
    float acc = 0.0f;
    {
        float4 a = c4p[0], b = c4p[1];
        r8[0] = __fmul_rn(a.x, a.x); r8[1] = __fmul_rn(a.y, a.y);
        r8[2] = __fmul_rn(a.z, a.z); r8[3] = __fmul_rn(a.w, a.w);
        r8[4] = __fmul_rn(b.x, b.x); r8[5] = __fmul_rn(b.y, b.y);
        r8[6] = __fmul_rn(b.z, b.z); r8[7] = __fmul_rn(b.w, b.w);
        acc = __fmaf_rn(xr[0], a.x, acc); acc = __fmaf_rn(xr[1], a.y, acc);
        acc = __fmaf_rn(xr[2], a.z, acc); acc = __fmaf_rn(xr[3], a.w, acc);
        acc = __fmaf_rn(xr[4], b.x, acc); acc = __fmaf_rn(xr[5], b.y, acc);
        acc = __fmaf_rn(xr[6], b.z, acc); acc = __fmaf_rn(xr[7], b.w, acc);
    }
    #pragma unroll
    for (int m = 1; m < 8; ++m) {
        float4 a = c4p[2 * m], b = c4p[2 * m + 1];
        r8[0] = __fadd_rn(r8[0], __fmul_rn(a.x, a.x));
        r8[1] = __fadd_rn(r8[1], __fmul_rn(a.y, a.y));
        r8[2] = __fadd_rn(r8[2], __fmul_rn(a.z, a.z));
        r8[3] = __fadd_rn(r8[3], __fmul_rn(a.w, a.w));
        r8[4] = __fadd_rn(r8[4], __fmul_rn(b.x, b.x));
        r8[5] = __fadd_rn(r8[5], __fmul_rn(b.y, b.y));
        r8[6] = __fadd_rn(r8[6], __fmul_rn(b.z, b.z));
        r8[7] = __fadd_rn(r8[7], __fmul_rn(b.w, b.w));
        const float* xm = xr + 8 * m;
        acc = __fmaf_rn(xm[0], a.x, acc); acc = __fmaf_rn(xm[1], a.y, acc);
        acc = __fmaf_rn(xm[2], a.z, acc); acc = __fmaf_rn(xm[3], a.w, acc);
        acc = __fmaf_rn(xm[4], b.x, acc); acc = __fmaf_rn(xm[5], b.y, acc);
        acc = __fmaf_rn(xm[6], b.z, acc); acc = __fmaf_rn(xm[7], b.w, acc);
    }
    float bn = np_combine8(r8);
    float t1 = __fadd_rn(an, bn);
    float d  = __fsub_rn(t1, __fmul_rn(2.0f, acc));
    return ((unsigned long long)fmap32(d) << 12) | (unsigned long long)k;
}

__global__ void vq_init_ws(double* ws) { ws[0] = 0.0; }

__global__ void vq_finalize_atomic(const double* __restrict__ ws,
                                   float* __restrict__ out_loss, int n_el) {
    out_loss[0] = (float)(1.25 * ws[0] / (double)n_el);
}

// reduces 2048 per-block partials (launched with 1024 threads)
__global__ void vq_finalize_part(const double* __restrict__ ws,
                                 float* __restrict__ out_loss, int n_el) {
    __shared__ double red[16];
    double v = ws[threadIdx.x] + ws[threadIdx.x + 1024];
    #pragma unroll
    for (int off = 32; off > 0; off >>= 1) v += __shfl_down(v, off, 64);
    if ((threadIdx.x & 63) == 0) red[threadIdx.x >> 6] = v;
    __syncthreads();
    if (threadIdx.x == 0) {
        double s = 0.0;
        #pragma unroll
        for (int i = 0; i < 16; ++i) s += red[i];
        out_loss[0] = (float)(1.25 * s / (double)n_el);
    }
}

// one-time fp32 -> bf16 codebook conversion + PRE-SWIZZLE into per-lane MFMA
// fragment order (proven r7): swz[(tile*2 + half)*64 + lane] = 8 bf16 of code
// (tile*16 + (lane&15)), dims half*32 + (lane>>4)*8 .. +7. Scan loads become
// 64 lanes x 16B CONTIGUOUS. Same f2bf bits as in-kernel conversion.
__global__ void vq_cvt_swz(const float* __restrict__ cb,
                           unsigned short* __restrict__ swz) {
    const int g = blockIdx.x * 256 + threadIdx.x;   // 0..8191 fragment groups
    const int lane = g & 63;
    const int half = (g >> 6) & 1;
    const int tile = g >> 7;                        // 0..63
    const int code = tile * 16 + (lane & 15);
    const int d0   = half * 32 + (lane >> 4) * 8;
    const float4* s = (const float4*)(cb + (size_t)code * DIM + d0);
    float4 v0 = s[0], v1 = s[1];
    short8 o;
    o[0] = (short)f2bf(v0.x); o[1] = (short)f2bf(v0.y);
    o[2] = (short)f2bf(v0.z); o[3] = (short)f2bf(v0.w);
    o[4] = (short)f2bf(v1.x); o[5] = (short)f2bf(v1.y);
    o[6] = (short)f2bf(v1.z); o[7] = (short)f2bf(v1.w);
    *(short8*)(swz + (size_t)g * 8) = o;
}

// Two-pass bnorm-free scan (capture-equivalence r4/r5; swizzled loads r7).
// Round-12: EXACT REVERT to the round-10 best (105.4 us total, vq_main ~41us,
// no spill). r11's single-scan (64-reg s-cache live across the smax barrier)
// was spilled by the allocator even under the (256,4)/128-VGPR cap — reverted.
// __launch_bounds__(256,4) caps at 128 VGPR: natural ~70-100 alloc, zero
// spill; MTILE=32 grid keeps 8 blocks/CU of work so residency lands at the
// VGPR-natural 5-6 waves/SIMD. 2-deep pipeline (r7-proven) for scan ILP.
template<int SWZ>
__global__ __launch_bounds__(THREADS, 4) void vq_main(
        const float* __restrict__ x,
        const float* __restrict__ cb,
        const unsigned short* __restrict__ swz,
        float* __restrict__ out_q,
        float* __restrict__ out_idx,
        double* __restrict__ wsd,
        int use_partials)
{
    __shared__ float xstage[MTILE * XP];        // 8704 B; reused as cpq in epilogue
    __shared__ float wsm[4][MTILE];             // per-wave row smax
    __shared__ unsigned short rlist[MTILE * RLP];
    __shared__ int   rcnt[MTILE];
    __shared__ float anorm[MTILE];
    __shared__ int   kstar[MTILE];
    __shared__ double lossd[MTILE];
    __shared__ int   ovfrows[MTILE];
    __shared__ int   ovfcnt;

    const int tid  = threadIdx.x;
    const int lane = tid & 63;
    const int wv   = tid >> 6;         // wave 0..3
    const int col  = lane & 15;
    const int quad = lane >> 4;        // 0..3
    const int r0   = blockIdx.x * MTILE;

    if (tid == 0) ovfcnt = 0;
    if (tid < MTILE) rcnt[tid] = 0;

    // ---- stage x rows into LDS, coalesced (exact fp32 bits); 8 thr/row ----
    {
        const int rr = tid >> 3, part = tid & 7;
        const float4* xs = (const float4*)(x + (size_t)(r0 + rr) * DIM + part * 8);
        float4 v0 = xs[0], v1 = xs[1];
        float* dst = &xstage[rr * XP + part * 8];
        *(float4*)&dst[0] = v0;
        *(float4*)&dst[4] = v1;
    }
    __syncthreads();

    // ---- A_n from staged rows (np-exact) ----
    if (tid < MTILE) anorm[tid] = np_norm64(&xstage[tid * XP]);

    // ---- A (row) fragments from LDS with in-lane bf16 convert ----
    short8 afr[RT_N][2];
    #pragma unroll
    for (int mt = 0; mt < RT_N; ++mt) {
        #pragma unroll
        for (int kh = 0; kh < 2; ++kh) {
            const float* ap = &xstage[(mt * 16 + col) * XP + kh * 32 + quad * 8];
            float4 a = *(const float4*)ap;
            float4 b = *(const float4*)(ap + 4);
            short8 s;
            s[0] = (short)f2bf(a.x); s[1] = (short)f2bf(a.y);
            s[2] = (short)f2bf(a.z); s[3] = (short)f2bf(a.w);
            s[4] = (short)f2bf(b.x); s[5] = (short)f2bf(b.y);
            s[6] = (short)f2bf(b.z); s[7] = (short)f2bf(b.w);
            afr[mt][kh] = s;
        }
    }

    // per-lane bases. SWZ path: wave wv's tile t is kt=4t+wv; fragment group
    // base = kt*128 + half*64 + lane (x8 shorts). Coalesced 1KB per load.
    const unsigned short* sw  = swz + (size_t)wv * 1024 + (size_t)lane * 8;
    const float*          bp0 = cb  + (size_t)(wv * 16 + col) * DIM + quad * 8;

    // ================= PASS 1: pure max scan (2-deep pipeline) =================
    float runsmax[RT_N];
    #pragma unroll
    for (int rt = 0; rt < RT_N; ++rt) runsmax[rt] = -3.4e38f;

    if constexpr (SWZ) {
        short8 c0a = *(const short8*)(sw);
        short8 c0b = *(const short8*)(sw + 512);
        short8 c1a = *(const short8*)(sw + 4096);
        short8 c1b = *(const short8*)(sw + 4096 + 512);
        #pragma unroll 1
        for (int t = 0; t < 16; t += 2) {
            short8 n0a, n0b, n1a, n1b;
            const bool more = (t + 2 < 16);
            if (more) {
                const unsigned short* nx = sw + (size_t)(t + 2) * 4096;
                n0a = *(const short8*)(nx);
                n0b = *(const short8*)(nx + 512);
                n1a = *(const short8*)(nx + 4096);
                n1b = *(const short8*)(nx + 4096 + 512);
            }
            #pragma unroll
            for (int rt = 0; rt < RT_N; ++rt) {
                f32x4 acc = {0.f, 0.f, 0.f, 0.f};
                acc = __builtin_amdgcn_mfma_f32_16x16x32_bf16(c0a, afr[rt][0], acc, 0, 0, 0);
                acc = __builtin_amdgcn_mfma_f32_16x16x32_bf16(c0b, afr[rt][1], acc, 0, 0, 0);
                runsmax[rt] = fmaxf(runsmax[rt],
                    fmaxf(fmaxf(acc[0], acc[1]), fmaxf(acc[2], acc[3])));
            }
            #pragma unroll
            for (int rt = 0; rt < RT_N; ++rt) {
                f32x4 acc = {0.f, 0.f, 0.f, 0.f};
                acc = __builtin_amdgcn_mfma_f32_16x16x32_bf16(c1a, afr[rt][0], acc, 0, 0, 0);
                acc = __builtin_amdgcn_mfma_f32_16x16x32_bf16(c1b, afr[rt][1], acc, 0, 0, 0);
                runsmax[rt] = fmaxf(runsmax[rt],
                    fmaxf(fmaxf(acc[0], acc[1]), fmaxf(acc[2], acc[3])));
            }
            if (more) { c0a = n0a; c0b = n0b; c1a = n1a; c1b = n1b; }
        }
    } else {
        #pragma unroll 1
        for (int t = 0; t < 16; ++t) {
            const float* p = bp0 + (size_t)t * 4096;
            float4 ca = *(const float4*)(p);
            float4 cb4 = *(const float4*)(p + 4);
            float4 cc = *(const float4*)(p + 32);
            float4 cd = *(const float4*)(p + 36);
            short8 b0, b1;
            b0[0] = (short)f2bf(ca.x);  b0[1] = (short)f2bf(ca.y);
            b0[2] = (short)f2bf(ca.z);  b0[3] = (short)f2bf(ca.w);
            b0[4] = (short)f2bf(cb4.x); b0[5] = (short)f2bf(cb4.y);
            b0[6] = (short)f2bf(cb4.z); b0[7] = (short)f2bf(cb4.w);
            b1[0] = (short)f2bf(cc.x);  b1[1] = (short)f2bf(cc.y);
            b1[2] = (short)f2bf(cc.z);  b1[3] = (short)f2bf(cc.w);
            b1[4] = (short)f2bf(cd.x);  b1[5] = (short)f2bf(cd.y);
            b1[6] = (short)f2bf(cd.z);  b1[7] = (short)f2bf(cd.w);
            #pragma unroll
            for (int rt = 0; rt < RT_N; ++rt) {
                f32x4 acc = {0.f, 0.f, 0.f, 0.f};
                acc = __builtin_amdgcn_mfma_f32_16x16x32_bf16(b0, afr[rt][0], acc, 0, 0, 0);
                acc = __builtin_amdgcn_mfma_f32_16x16x32_bf16(b1, afr[rt][1], acc, 0, 0, 0);
                runsmax[rt] = fmaxf(runsmax[rt],
                    fmaxf(fmaxf(acc[0], acc[1]), fmaxf(acc[2], acc[3])));
            }
        }
    }

    // merge: quads (same row) then waves via LDS -> exact final smax per row
    #pragma unroll
    for (int rt = 0; rt < RT_N; ++rt) {
        float mw = fmaxf(runsmax[rt], __shfl_xor(runsmax[rt], 16, 64));
        mw = fmaxf(mw, __shfl_xor(mw, 32, 64));
        if (quad == 0) wsm[wv][rt * 16 + col] = mw;
    }
    __syncthreads();
    float scut[RT_N];
    #pragma unroll
    for (int rt = 0; rt < RT_N; ++rt) {
        const int row = rt * 16 + col;
        float sm = fmaxf(fmaxf(wsm[0][row], wsm[1][row]),
                         fmaxf(wsm[2][row], wsm[3][row]));
        scut[rt] = sm - SMARG;
    }

    // ================= PASS 2: capture vs fixed cut =================
    if constexpr (SWZ) {
        short8 c0a = *(const short8*)(sw);
        short8 c0b = *(const short8*)(sw + 512);
        short8 c1a = *(const short8*)(sw + 4096);
        short8 c1b = *(const short8*)(sw + 4096 + 512);
        #pragma unroll 1
        for (int t = 0; t < 16; t += 2) {
            short8 n0a, n0b, n1a, n1b;
            const bool more = (t + 2 < 16);
            if (more) {
                const unsigned short* nx = sw + (size_t)(t + 2) * 4096;
                n0a = *(const short8*)(nx);
                n0b = *(const short8*)(nx + 512);
                n1a = *(const short8*)(nx + 4096);
                n1b = *(const short8*)(nx + 4096 + 512);
            }
            const int kb0 = (t * 4 + wv) * 16 + quad * 4;
            const int kb1 = ((t + 1) * 4 + wv) * 16 + quad * 4;
            #pragma unroll
            for (int rt = 0; rt < RT_N; ++rt) {
                f32x4 acc = {0.f, 0.f, 0.f, 0.f};
                acc = __builtin_amdgcn_mfma_f32_16x16x32_bf16(c0a, afr[rt][0], acc, 0, 0, 0);
                acc = __builtin_amdgcn_mfma_f32_16x16x32_bf16(c0b, afr[rt][1], acc, 0, 0, 0);
                float m = fmaxf(fmaxf(acc[0], acc[1]), fmaxf(acc[2], acc[3]));
                if (m >= scut[rt]) {           // rare (~2-3 hits/row whole pass)
                    const int row = rt * 16 + col;
                    #pragma unroll
                    for (int e = 0; e < 4; ++e) {
                        if (acc[e] >= scut[rt]) {
                            int p2 = atomicAdd(&rcnt[row], 1);
                            if (p2 < RCAP)
                                rlist[row * RLP + p2] = (unsigned short)(kb0 + e);
                        }
                    }
                }
            }
            #pragma unroll
            for (int rt = 0; rt < RT_N; ++rt) {
                f32x4 acc = {0.f, 0.f, 0.f, 0.f};
                acc = __builtin_amdgcn_mfma_f32_16x16x32_bf16(c1a, afr[rt][0], acc, 0, 0, 0);
                acc = __builtin_amdgcn_mfma_f32_16x16x32_bf16(c1b, afr[rt][1], acc, 0, 0, 0);
                float m = fmaxf(fmaxf(acc[0], acc[1]), fmaxf(acc[2], acc[3]));
                if (m >= scut[rt]) {
                    const int row = rt * 16 + col;
                    #pragma unroll
                    for (int e = 0; e < 4; ++e) {
                        if (acc[e] >= scut[rt]) {
                            int p2 = atomicAdd(&rcnt[row], 1);
                            if (p2 < RCAP)
                                rlist[row * RLP + p2] = (unsigned short)(kb1 + e);
                        }
                    }
                }
            }
            if (more) { c0a = n0a; c0b = n0b; c1a = n1a; c1b = n1b; }
        }
    } else {
        #pragma unroll 1
        for (int t = 0; t < 16; ++t) {
            const float* p = bp0 + (size_t)t * 4096;
            const int kb = (t * 4 + wv) * 16 + quad * 4;
            float4 ca = *(const float4*)(p);
            float4 cb4 = *(const float4*)(p + 4);
            float4 cc = *(const float4*)(p + 32);
            float4 cd = *(const float4*)(p + 36);
            short8 b0, b1;
            b0[0] = (short)f2bf(ca.x);  b0[1] = (short)f2bf(ca.y);
            b0[2] = (short)f2bf(ca.z);  b0[3] = (short)f2bf(ca.w);
            b0[4] = (short)f2bf(cb4.x); b0[5] = (short)f2bf(cb4.y);
            b0[6] = (short)f2bf(cb4.z); b0[7] = (short)f2bf(cb4.w);
            b1[0] = (short)f2bf(cc.x);  b1[1] = (short)f2bf(cc.y);
            b1[2] = (short)f2bf(cc.z);  b1[3] = (short)f2bf(cc.w);
            b1[4] = (short)f2bf(cd.x);  b1[5] = (short)f2bf(cd.y);
            b1[6] = (short)f2bf(cd.z);  b1[7] = (short)f2bf(cd.w);
            #pragma unroll
            for (int rt = 0; rt < RT_N; ++rt) {
                f32x4 acc = {0.f, 0.f, 0.f, 0.f};
                acc = __builtin_amdgcn_mfma_f32_16x16x32_bf16(b0, afr[rt][0], acc, 0, 0, 0);
                acc = __builtin_amdgcn_mfma_f32_16x16x32_bf16(b1, afr[rt][1], acc, 0, 0, 0);
                float m = fmaxf(fmaxf(acc[0], acc[1]), fmaxf(acc[2], acc[3]));
                if (m >= scut[rt]) {
                    const int row = rt * 16 + col;
                    #pragma unroll
                    for (int e = 0; e < 4; ++e) {
                        if (acc[e] >= scut[rt]) {
                            int p2 = atomicAdd(&rcnt[row], 1);
                            if (p2 < RCAP)
                                rlist[row * RLP + p2] = (unsigned short)(kb + e);
                        }
                    }
                }
            }
        }
    }
    __syncthreads();   // rlist complete

    // ---- refine: 8 threads/row (j strided), np-bit-exact keys, shfl merge ----
    {
        const int r  = tid >> 3;      // row 0..31 (threads 8r..8r+7: same wave)
        const int j0 = tid & 7;
        const int n  = rcnt[r];
        unsigned long long best = ~0ULL;
        if (n <= RCAP) {
            const float an = anorm[r];
            const float* xr = &xstage[r * XP];
            for (int j = j0; j < n; j += 8) {
                const int k = rlist[r * RLP + j];
                unsigned long long key = np_key_full(xr, cb + (size_t)k * DIM, an, k);
                best = (key < best) ? key : best;
            }
        }
        unsigned long long o = __shfl_xor(best, 1, 64);
        best = (o < best) ? o : best;
        o = __shfl_xor(best, 2, 64);
        best = (o < best) ? o : best;
        o = __shfl_xor(best, 4, 64);
        best = (o < best) ? o : best;
        if (j0 == 0) {
            if (n > RCAP || best == ~0ULL) {
                int si = atomicAdd(&ovfcnt, 1);
                ovfrows[si] = r;
            } else {
                kstar[r] = (int)(best & 0xFFFULL);
                lossd[r] = (double)funmap32((unsigned int)(best >> 12));
            }
        }
    }
    __syncthreads();

    // ---- wave-parallel exhaustive np fallback for overflowed rows (rare) ----
    const int ovfn = ovfcnt;
    for (int i = wv; i < ovfn; i += 4) {
        const int row = ovfrows[i];
        const float* xr2 = &xstage[row * XP];   // same-address LDS broadcasts
        const float an2 = anorm[row];
        unsigned long long b2 = ~0ULL;
        for (int j = 0; j < 16; ++j) {
            int k = lane * 16 + j;
            unsigned long long key = np_key_full(xr2, cb + (size_t)k * DIM, an2, k);
            b2 = (key < b2) ? key : b2;
        }
        #pragma unroll
        for (int off = 1; off < 64; off <<= 1) {
            unsigned long long o = __shfl_xor(b2, off, 64);
            b2 = (o < b2) ? o : b2;
        }
        if (lane == 0) {
            kstar[row] = (int)(b2 & 0xFFFULL);
            lossd[row] = (double)funmap32((unsigned int)(b2 >> 12));
        }
    }
    __syncthreads();

    // ---- epilogue: indices; stage selected cb rows into LDS (de-gathered),
    //      then transposed quantized stores; loss reduce (verified) ----
    if (tid < MTILE) out_idx[r0 + tid] = (float)kstar[tid];

    float* cpq = xstage;   // xstage dead from here; reuse with pitch CQP=66
    {
        const int r = tid >> 3, part = tid & 7;
        const int kq = kstar[r];
        const float4* cp = (const float4*)(cb + (size_t)kq * DIM + part * 8);
        float4 v0 = cp[0], v1 = cp[1];
        float* dst = &cpq[r * CQP + part * 8];   // 8B-aligned: float2 writes
        *(float2*)&dst[0] = make_float2(v0.x, v0.y);
        *(float2*)&dst[2] = make_float2(v0.z, v0.w);
        *(float2*)&dst[4] = make_float2(v1.x, v1.y);
        *(float2*)&dst[6] = make_float2(v1.z, v1.w);
    }
    __syncthreads();

    const int bb = r0 / T_LEN;
    const int t0 = r0 % T_LEN;
    const int t  = tid & 31, part = tid >> 5;   // part 0..7
    #pragma unroll
    for (int it = 0; it < 8; ++it) {
        int d = it * 8 + part;
        out_q[((size_t)bb * DIM + d) * T_LEN + (t0 + t)] = cpq[t * CQP + d];
    }

    if (tid < 64) {
        double v = (tid < MTILE) ? lossd[tid] : 0.0;
        #pragma unroll
        for (int off = 32; off > 0; off >>= 1) v += __shfl_down(v, off, 64);
        if (tid == 0) {
            if (use_partials) wsd[blockIdx.x] = v;
            else atomicAdd(wsd, v);
        }
    }
}

extern "C" void kernel_launch(void* const* d_in, const int* in_sizes, int n_in,
                              void* d_out, int out_size, void* d_ws, size_t ws_size,
                              hipStream_t stream) {
    const float* x  = (const float*)d_in[0];
    const float* cb = (const float*)d_in[1];
    float* out = (float*)d_out;

    const int n_x = in_sizes[0];           // 4194304
    const int n_rows = n_x / DIM;          // 65536
    const int n_blocks = n_rows / MTILE;   // 2048

    float* out_q    = out;                    // [B, D, T]
    float* out_loss = out + (size_t)n_x;      // scalar
    float* out_idx  = out + (size_t)n_x + 1;  // [B, T] as float
    double* wsd = (double*)d_ws;

    const size_t need_part = (size_t)n_blocks * sizeof(double);
    const int use_partials = (ws_size >= need_part) ? 1 : 0;
    const size_t cb_off = use_partials ? ((need_part + 15) & ~(size_t)15) : (size_t)16;
    const int use_swz = (ws_size >= cb_off + 1024 * DIM * sizeof(unsigned short)) ? 1 : 0;
    unsigned short* swz = (unsigned short*)((char*)d_ws + cb_off);

    if (!use_partials) vq_init_ws<<<1, 1, 0, stream>>>(wsd);
    if (use_swz) {
        vq_cvt_swz<<<32, 256, 0, stream>>>(cb, swz);
        vq_main<1><<<n_blocks, THREADS, 0, stream>>>(x, cb, swz, out_q, out_idx,
                                                     wsd, use_partials);
    } else {
        vq_main<0><<<n_blocks, THREADS, 0, stream>>>(x, cb, (const unsigned short*)cb,
                                                     out_q, out_idx, wsd, use_partials);
    }
    if (use_partials) vq_finalize_part<<<1, 1024, 0, stream>>>(wsd, out_loss, n_x);
    else vq_finalize_atomic<<<1, 1, 0, stream>>>(wsd, out_loss, n_x);
}